// Round 15
// baseline (1009.452 us; speedup 1.0000x reference)
//
#include <hip/hip_runtime.h>
#include <stdint.h>

#define B      256
#define DIN    700
#define T      250
#define H      1024
#define DOUT   20
#define NW_IN  11     // u64 words for 700 input bits
#define NW_INP 12     // padded
#define LMAX   160    // per-row list capacity (4 packed sublists, chunk-2 padded)
#define JSENT2 22512  // LDS sentinel: pre-swizzled offset of local row 175 (zeros)

typedef unsigned long long u64;

// ---------------- prep: weights transpose + spike bitpack (merged) ----------------
__global__ void prep_all(const float* __restrict__ W_hid,
                         const float* __restrict__ W_out,
                         const float* __restrict__ spk,
                         float* __restrict__ Wt,
                         float* __restrict__ WoT,
                         u64* __restrict__ bits) {
    if (blockIdx.x < 2800) {
        int idx = blockIdx.x * 256 + threadIdx.x;
        int d = idx / H;
        int h = idx - d * H;
        Wt[idx] = W_hid[h * DIN + d];
    } else if (blockIdx.x < 2880) {
        int i = (blockIdx.x - 2800) * 256 + threadIdx.x;   // 0..20479
        int h = i / DOUT;
        int o = i - h * DOUT;
        WoT[i] = W_out[o * H + h];
    } else {
        int bid = blockIdx.x - 2880;     // 0..1023
        int b  = bid >> 2;
        int wc = bid & 3;
        int t  = threadIdx.x;
        if (t >= T) return;
        int w0 = wc * 3;
        int w1 = (wc == 3) ? NW_IN : w0 + 3;
        const float* base = spk + (size_t)b * DIN * T + t;
        for (int w = w0; w < w1; ++w) {
            u64 m = 0;
#pragma unroll
            for (int j = 0; j < 64; ++j) {
                int d = (w << 6) + j;
                if (d < DIN) {
                    float x = base[(size_t)d * T];
                    m |= (u64)(x > 0.5f) << j;
                }
            }
            bits[((size_t)b * T + t) * NW_INP + w] = m;
        }
    }
}

// ---------------- prep: 4 packed sublists of pre-swizzled LDS byte offsets ----
// Sublist p: j in [175p,175p+175), local jl = j-175p. Entry = jl*128 +
// ((jl&7)<<4); lane addr = entry ^ (li<<4). CHUNK-2 padded (was chunk-4:
// 8.6% of gather ds_reads were sentinel waste; chunk-2 -> ~2.9%) with JSENT2
// (zero row 175). nrow packs 4 chunk counts (u8 each, chunk = 2 entries).
__global__ void __launch_bounds__(256)
prep_lists2(const u64* __restrict__ bits,
            unsigned short* __restrict__ lists,
            unsigned* __restrict__ nrow) {
    __shared__ unsigned short scr[4][LMAX];

    int wv   = threadIdx.x >> 6;
    int lane = threadIdx.x & 63;
    int row  = blockIdx.x * 4 + wv;   // 16000 blocks -> exactly 64000 rows

    const u64* wp = bits + (size_t)row * NW_INP;
    u64 mw = (lane < NW_IN) ? wp[lane] : 0ull;

    for (int i = lane; i < LMAX; i += 64) scr[wv][i] = (unsigned short)JSENT2;

    u64 lowmask = (1ull << lane) - 1ull;
    int pos = 0;
    unsigned counts = 0;

#pragma unroll
    for (int p = 0; p < 4; ++p) {
        int jlo = 175 * p, jhi = jlo + 175;
        int n = 0;
        for (int k = jlo >> 6; k <= (jhi - 1) >> 6; ++k) {
            u64 m = __shfl(mw, k);
            int lo = jlo - (k << 6);
            int hi = jhi - (k << 6);
            if (lo > 0)  m &= ~((1ull << lo) - 1ull);
            if (hi < 64) m &= (1ull << hi) - 1ull;
            if ((m >> lane) & 1ull) {
                int q = pos + n + __popcll(m & lowmask);
                int jl = (k << 6) + lane - jlo;
                if (q < LMAX)
                    scr[wv][q] = (unsigned short)(jl * 128 + ((jl & 7) << 4));
            }
            n += __popcll(m);
        }
        int c = (n + 1) >> 1;           // chunks of 2
        counts |= (unsigned)c << (8 * p);
        pos += c * 2;
    }

    if (lane == 0) nrow[row] = counts;
    __syncthreads();

    const unsigned* s32 = (const unsigned*)scr[wv];
    unsigned* g32 = (unsigned*)(lists + (size_t)row * LMAX);
    g32[lane] = s32[lane];
    if (lane < 16) g32[64 + lane] = s32[64 + lane];
}

// ---------------- prep: counting sort per (b, sublist, t-half) ----------------
// Keys are now chunk-2 counts (<=~18 realistic; cap 31 only merges top buckets).
__global__ void __launch_bounds__(256)
sort_rows(const unsigned* __restrict__ nrow,
          unsigned char* __restrict__ perm) {
    __shared__ int cnt[8][32];
    __shared__ int off[8][32];
    int b = blockIdx.x, tid = threadIdx.x;
    cnt[tid >> 5][tid & 31] = 0;
    __syncthreads();
    unsigned cc = 0; int half = 0, lt = 0;
    if (tid < T) {
        cc = nrow[b * T + tid];
        half = tid >= 125;
        lt = tid - half * 125;
#pragma unroll
        for (int p = 0; p < 4; ++p) {
            int c = (cc >> (8 * p)) & 0xff; if (c > 31) c = 31;
            atomicAdd(&cnt[p * 2 + half][c], 1);
        }
    }
    __syncthreads();
    if (tid < 8) {
        int s = 0;
        for (int i = 0; i < 32; ++i) { off[tid][i] = s; s += cnt[tid][i]; cnt[tid][i] = 0; }
    }
    __syncthreads();
    if (tid < T) {
#pragma unroll
        for (int p = 0; p < 4; ++p) {
            int c = (cc >> (8 * p)) & 0xff; if (c > 31) c = 31;
            int sidx = p * 2 + half;
            int rank = off[sidx][c] + atomicAdd(&cnt[sidx][c], 1);
            perm[((size_t)b * 8 + sidx) * 128 + rank] = (unsigned char)lt;
        }
    }
}

// ---------------- hidden layer: 38.5 KB LDS -> 4 blocks/CU (32 waves/CU) ----
// r14-proven structure (u32[b][s][t] hsbits layout, no RMW); gather loop now
// consumes chunk-2 lists (uint load = 2 entries) -> ~6% fewer sentinel
// ds_read_b128 on the saturated DS port. Summation order unchanged.
__global__ void __launch_bounds__(512, 8)
hidden_slice3(const unsigned short* __restrict__ lists,
              const unsigned* __restrict__ nrow,
              const unsigned char* __restrict__ perm,
              const float* __restrict__ Wt,
              const float* __restrict__ hs0,
              const float* __restrict__ hv0,
              unsigned* __restrict__ hsb32) {
    __shared__ float wlds[176 * 32];   // 22,528 B (row 175 = zeros)
    __shared__ float cur[125 * 32];    // 16,000 B

    int s    = blockIdx.x;        // 0..31 h-slice
    int b    = blockIdx.y;        // 0..255
    int tid  = threadIdx.x;
    int wv   = tid >> 6;
    int lane = tid & 63;
    int g    = lane >> 3;
    int li   = lane & 7;
    int lxor = li << 4;
    int l    = lane & 31;

    float keep = 0.0f;
    if (wv == 0) {
        int h = s * 32 + l;
        keep = hv0[b * H + h] * 0.5f * (1.0f - hs0[b * H + h]);
    }
    unsigned* hp = hsb32 + ((size_t)b * 32 + s) * T;   // this block's 250-u32 run

    for (int th = 0; th < 2; ++th) {
        for (int p = 0; p < 4; ++p) {
            // ---- stage quarter-Wt slice, swizzled: slot = lis ^ (jl&7) ----
            {
                int jr  = tid >> 3;            // 0..63
                int lis = tid & 7;
#pragma unroll
                for (int bj = 0; bj < 192; bj += 64) {
                    int jl = bj + jr;
                    if (jl < 176) {
                        float4 v = make_float4(0.0f, 0.0f, 0.0f, 0.0f);
                        if (jl < 175)
                            v = *(const float4*)(Wt + (size_t)(p * 175 + jl) * H + s * 32 + lis * 4);
                        *(float4*)((char*)wlds + jl * 128 + ((lis ^ (jl & 7)) << 4)) = v;
                    }
                }
            }
            __syncthreads();

            const unsigned char* pm = perm + ((size_t)b * 8 + p * 2 + th) * 128;

            // ---- gather: 125 rows, 64 groups -> 2 sweeps ----
#pragma unroll
            for (int sweep = 0; sweep < 2; ++sweep) {
                int rr = sweep * 64 + wv * 8 + g;
                if (rr < 125) {
                    int lr  = pm[rr];
                    int r   = th * 125 + lr;
                    int row = b * T + r;
                    unsigned cc = nrow[row];
                    int c = (cc >> (8 * p)) & 0xff;
                    int offc = 0;
                    if (p > 0) offc += (cc & 0xff);
                    if (p > 1) offc += ((cc >> 8) & 0xff);
                    if (p > 2) offc += ((cc >> 16) & 0xff);
                    const unsigned* qp = (const unsigned*)(lists + (size_t)row * LMAX + offc * 2);
                    char* cp = (char*)cur + lr * 128 + ((li ^ (lr & 7)) << 4);

                    float a0, a1, a2, a3;
                    if (p == 0) {
                        a0 = a1 = a2 = a3 = 0.0f;
                    } else {
                        float4 cv = *(const float4*)cp;
                        a0 = cv.x; a1 = cv.y; a2 = cv.z; a3 = cv.w;
                    }

                    if (c > 0) {
                        unsigned w1 = qp[0];
                        int ch = 0;
                        for (;;) {
                            unsigned nw = (ch + 1 < c) ? qp[ch + 1] : w1;
                            int e0 = w1 & 0xffff, e1 = w1 >> 16;
                            float4 v0 = *(const float4*)((char*)wlds + (e0 ^ lxor));
                            float4 v1 = *(const float4*)((char*)wlds + (e1 ^ lxor));
                            a0 += v0.x; a1 += v0.y; a2 += v0.z; a3 += v0.w;
                            a0 += v1.x; a1 += v1.y; a2 += v1.z; a3 += v1.w;
                            ++ch;
                            if (ch >= c) break;
                            w1 = nw;
                        }
                    }
                    float4 o; o.x = a0; o.y = a1; o.z = a2; o.w = a3;
                    *(float4*)cp = o;
                }
            }
            __syncthreads();
        }

        // ---- scan this t-half: wave 0 (lanes 32-63 mirror), 32 h ----
        if (wv == 0) {
            for (int lt = 0; lt < 125; ++lt) {
                float cv = *(const float*)((char*)cur + lt * 128 +
                                           (((l >> 2) ^ (lt & 7)) << 4) + (l & 3) * 4);
                float hv = keep + cv;
                bool sp = hv > 0.5f;
                keep = sp ? 0.0f : hv * 0.5f;
                u64 ball = __ballot(sp);
                if (lane == 0)
                    hp[th * 125 + lt] = (unsigned)ball;
            }
        }
        __syncthreads();   // protect cur before next half overwrites
    }
}

// ---------------- fallback: round-0 fused hidden kernel (new hsbits layout) ----
__global__ void __launch_bounds__(1024)
hidden_fused(const u64* __restrict__ bits,
             const float* __restrict__ Wt,
             const float* __restrict__ hs0,
             const float* __restrict__ hv0,
             unsigned* __restrict__ hsb32) {
    __shared__ int idx_l[2][256];

    int b = blockIdx.x;
    int h = threadIdx.x;
    int wv   = h >> 6;
    int lane = h & 63;

    float keep = hv0[b * H + h] * 0.5f * (1.0f - hs0[b * H + h]);

    const u64* bb = bits + (size_t)b * T * NW_INP;

    for (int t = 0; t < T; ++t) {
        const u64* wp = bb + (size_t)t * NW_INP;
        u64 w[NW_IN];
#pragma unroll
        for (int k = 0; k < NW_IN; ++k) w[k] = wp[k];

        int base[NW_IN + 1];
        base[0] = 0;
#pragma unroll
        for (int k = 0; k < NW_IN; ++k) base[k + 1] = base[k] + __popcll(w[k]);
        int n = base[NW_IN];

        int buf = t & 1;
        if (wv < NW_IN) {
            u64 m = w[wv];
            if ((m >> lane) & 1ull) {
                int pos = base[wv] + __popcll(m & ((1ull << lane) - 1ull));
                idx_l[buf][pos] = (wv << 6) + lane;
            }
        }
        __syncthreads();

        const int* il = idx_l[buf];
        float cur2 = 0.0f;
        int i = 0;
        for (; i + 8 <= n; i += 8) {
            int j0 = il[i + 0], j1 = il[i + 1], j2 = il[i + 2], j3 = il[i + 3];
            int j4 = il[i + 4], j5 = il[i + 5], j6 = il[i + 6], j7 = il[i + 7];
            float v0 = Wt[(size_t)j0 * H + h];
            float v1 = Wt[(size_t)j1 * H + h];
            float v2 = Wt[(size_t)j2 * H + h];
            float v3 = Wt[(size_t)j3 * H + h];
            float v4 = Wt[(size_t)j4 * H + h];
            float v5 = Wt[(size_t)j5 * H + h];
            float v6 = Wt[(size_t)j6 * H + h];
            float v7 = Wt[(size_t)j7 * H + h];
            cur2 += v0; cur2 += v1; cur2 += v2; cur2 += v3;
            cur2 += v4; cur2 += v5; cur2 += v6; cur2 += v7;
        }
        for (; i < n; ++i) cur2 += Wt[(size_t)il[i] * H + h];

        float hv = keep + cur2;
        bool sp = hv > 0.5f;
        keep = sp ? 0.0f : hv * 0.5f;
        u64 ball = __ballot(sp);
        if (lane == 0) {
            hsb32[((size_t)b * 32 + 2 * wv + 0) * T + t] = (unsigned)ball;
            hsb32[((size_t)b * 32 + 2 * wv + 1) * T + t] = (unsigned)(ball >> 32);
        }
    }
}

// ---------------- output currents v2: LDS-staged WoT, 3 rows/wave ----------------
__global__ void __launch_bounds__(512)
out_currents2(const unsigned* __restrict__ hsb32,
              const float* __restrict__ WoT,
              float* __restrict__ Iout) {
    __shared__ float wot[H * DOUT];   // 81,920 B

    int tid = threadIdx.x;
    {
        const float4* src = (const float4*)WoT;
        float4* dst = (float4*)wot;
#pragma unroll
        for (int k = 0; k < 10; ++k)
            dst[k * 512 + tid] = src[k * 512 + tid];
    }
    __syncthreads();

    int wv   = tid >> 6;
    int lane = tid & 63;
    int sub  = lane / 20;             // 0..3 (3 = idle)
    int o    = lane - sub * 20;
    int row  = blockIdx.x * 24 + wv * 3 + sub;
    if (sub >= 3 || row >= B * T) return;

    int b = row / T;
    int t = row - b * T;
    const unsigned* hb = hsb32 + (size_t)b * 32 * T + t;

    unsigned w[32];
#pragma unroll
    for (int k = 0; k < 32; ++k) w[k] = hb[(size_t)k * T];

    float acc = 0.0f;
#pragma unroll
    for (int k = 0; k < 32; ++k) {
        unsigned m = w[k];
        const float* basep = wot + k * 32 * DOUT + o;
        while (m) {
            int h0 = __builtin_ctz(m);
            m &= m - 1;
            acc += basep[h0 * DOUT];
        }
    }
    Iout[(size_t)row * DOUT + o] = acc;
}

// ---------------- output scan + spike count (LDS-staged) ----------------
__global__ void __launch_bounds__(256)
out_scan(const float* __restrict__ Iout,
         const float* __restrict__ os0,
         const float* __restrict__ ov0,
         float* __restrict__ outp) {
    __shared__ float pan[T * DOUT];   // 20,000 B

    int b   = blockIdx.x;
    int tid = threadIdx.x;

    const float* src = Iout + (size_t)b * T * DOUT;
#pragma unroll
    for (int k = 0; k < 20; ++k) {
        int i = k * 256 + tid;
        if (i < T * DOUT) pan[i] = src[i];
    }
    __syncthreads();

    if (tid < DOUT) {
        int o = tid;
        int idx = b * DOUT + o;
        float ov = ov0[idx];
        float os = os0[idx];
        float keep = ov * 0.5f * (1.0f - os);
        float cnt = 0.0f;
#pragma unroll 5
        for (int t = 0; t < T; ++t) {
            float v = keep + pan[t * DOUT + o];
            float sp = (v > 0.5f) ? 1.0f : 0.0f;
            cnt += sp;
            keep = v * 0.5f * (1.0f - sp);
        }
        outp[idx] = cnt;
    }
}

extern "C" void kernel_launch(void* const* d_in, const int* in_sizes, int n_in,
                              void* d_out, int out_size, void* d_ws, size_t ws_size,
                              hipStream_t stream) {
    const float* spike = (const float*)d_in[0];   // [256][700][250]
    const float* W_hid = (const float*)d_in[1];   // [1024][700]
    const float* W_out = (const float*)d_in[2];   // [20][1024]
    const float* hs0   = (const float*)d_in[3];   // [256][1024]
    const float* hv0   = (const float*)d_in[4];
    const float* os0   = (const float*)d_in[5];   // [256][20]
    const float* ov0   = (const float*)d_in[6];
    float* outp = (float*)d_out;                  // [256][20]

    char* ws = (char*)d_ws;
    float*          Wt     = (float*)(ws);                      // 2,867,200 B
    float*          WoT    = (float*)(ws + 2867200);            //    81,920 B
    u64*            bits   = (u64*)  (ws + 2949120);            // 6,144,000 B
    unsigned*       hsb32  = (unsigned*)(ws + 9093120);         // 8,192,000 B
    float*          Iout   = (float*)(ws + 17285120);           // 5,120,000 B
    unsigned short* lists  = (unsigned short*)(ws + 22405120);  // 20,480,000 B
    unsigned*       nrow   = (unsigned*)(ws + 42885120);        //   256,000 B
    unsigned char*  perm   = (unsigned char*)(ws + 43141120);   //   262,144 B
    const size_t need = 43403264;

    prep_all<<<3904, 256, 0, stream>>>(W_hid, W_out, spike, Wt, WoT, bits);

    if (ws_size >= need) {
        prep_lists2<<<16000, 256, 0, stream>>>(bits, lists, nrow);
        sort_rows<<<B, 256, 0, stream>>>(nrow, perm);
        hidden_slice3<<<dim3(32, 256), 512, 0, stream>>>(lists, nrow, perm, Wt, hs0, hv0, hsb32);
    } else {
        hidden_fused<<<B, 1024, 0, stream>>>(bits, Wt, hs0, hv0, hsb32);
    }

    out_currents2<<<2667, 512, 0, stream>>>(hsb32, WoT, Iout);
    out_scan<<<B, 256, 0, stream>>>(Iout, os0, ov0, outp);
}

// Round 16
// 953.163 us; speedup vs baseline: 1.0591x; 1.0591x over previous
//
#include <hip/hip_runtime.h>
#include <stdint.h>

#define B      256
#define DIN    700
#define T      250
#define H      1024
#define DOUT   20
#define NW_IN  11     // u64 words for 700 input bits
#define NW_INP 12     // padded
#define LMAX   160    // per-row list capacity (4 packed sublists, chunk-4 padded)
#define JSENT2 22512  // LDS sentinel: pre-swizzled offset of local row 175 (zeros)

typedef unsigned long long u64;

// ---------------- prep: weights transpose + spike bitpack (merged) ----------------
__global__ void prep_all(const float* __restrict__ W_hid,
                         const float* __restrict__ W_out,
                         const float* __restrict__ spk,
                         float* __restrict__ Wt,
                         float* __restrict__ WoT,
                         u64* __restrict__ bits) {
    if (blockIdx.x < 2800) {
        int idx = blockIdx.x * 256 + threadIdx.x;
        int d = idx / H;
        int h = idx - d * H;
        Wt[idx] = W_hid[h * DIN + d];
    } else if (blockIdx.x < 2880) {
        int i = (blockIdx.x - 2800) * 256 + threadIdx.x;   // 0..20479
        int h = i / DOUT;
        int o = i - h * DOUT;
        WoT[i] = W_out[o * H + h];
    } else {
        int bid = blockIdx.x - 2880;     // 0..1023
        int b  = bid >> 2;
        int wc = bid & 3;
        int t  = threadIdx.x;
        if (t >= T) return;
        int w0 = wc * 3;
        int w1 = (wc == 3) ? NW_IN : w0 + 3;
        const float* base = spk + (size_t)b * DIN * T + t;
        for (int w = w0; w < w1; ++w) {
            u64 m = 0;
#pragma unroll
            for (int j = 0; j < 64; ++j) {
                int d = (w << 6) + j;
                if (d < DIN) {
                    float x = base[(size_t)d * T];
                    m |= (u64)(x > 0.5f) << j;
                }
            }
            bits[((size_t)b * T + t) * NW_INP + w] = m;
        }
    }
}

// ---------------- prep: 4 packed sublists of pre-swizzled LDS byte offsets ----
// (r7/r14-proven) Sublist p: j in [175p,175p+175), local jl = j-175p. Entry =
// jl*128 + ((jl&7)<<4); lane addr = entry ^ (li<<4). Chunk-4 padded with
// JSENT2 (zero row 175). nrow packs 4 chunk counts (u8 each).
__global__ void __launch_bounds__(256)
prep_lists2(const u64* __restrict__ bits,
            unsigned short* __restrict__ lists,
            unsigned* __restrict__ nrow) {
    __shared__ unsigned short scr[4][LMAX];

    int wv   = threadIdx.x >> 6;
    int lane = threadIdx.x & 63;
    int row  = blockIdx.x * 4 + wv;   // 16000 blocks -> exactly 64000 rows

    const u64* wp = bits + (size_t)row * NW_INP;
    u64 mw = (lane < NW_IN) ? wp[lane] : 0ull;

    for (int i = lane; i < LMAX; i += 64) scr[wv][i] = (unsigned short)JSENT2;

    u64 lowmask = (1ull << lane) - 1ull;
    int pos = 0;
    unsigned counts = 0;

#pragma unroll
    for (int p = 0; p < 4; ++p) {
        int jlo = 175 * p, jhi = jlo + 175;
        int n = 0;
        for (int k = jlo >> 6; k <= (jhi - 1) >> 6; ++k) {
            u64 m = __shfl(mw, k);
            int lo = jlo - (k << 6);
            int hi = jhi - (k << 6);
            if (lo > 0)  m &= ~((1ull << lo) - 1ull);
            if (hi < 64) m &= (1ull << hi) - 1ull;
            if ((m >> lane) & 1ull) {
                int q = pos + n + __popcll(m & lowmask);
                int jl = (k << 6) + lane - jlo;
                if (q < LMAX)
                    scr[wv][q] = (unsigned short)(jl * 128 + ((jl & 7) << 4));
            }
            n += __popcll(m);
        }
        int c = (n + 3) >> 2;           // chunks of 4
        counts |= (unsigned)c << (8 * p);
        pos += c * 4;
    }

    if (lane == 0) nrow[row] = counts;
    __syncthreads();

    const unsigned* s32 = (const unsigned*)scr[wv];
    unsigned* g32 = (unsigned*)(lists + (size_t)row * LMAX);
    g32[lane] = s32[lane];
    if (lane < 16) g32[64 + lane] = s32[64 + lane];
}

// ---------------- prep: counting sort per (b, sublist, t-half) ----------------
__global__ void __launch_bounds__(256)
sort_rows(const unsigned* __restrict__ nrow,
          unsigned char* __restrict__ perm) {
    __shared__ int cnt[8][32];
    __shared__ int off[8][32];
    int b = blockIdx.x, tid = threadIdx.x;
    cnt[tid >> 5][tid & 31] = 0;
    __syncthreads();
    unsigned cc = 0; int half = 0, lt = 0;
    if (tid < T) {
        cc = nrow[b * T + tid];
        half = tid >= 125;
        lt = tid - half * 125;
#pragma unroll
        for (int p = 0; p < 4; ++p) {
            int c = (cc >> (8 * p)) & 0xff; if (c > 31) c = 31;
            atomicAdd(&cnt[p * 2 + half][c], 1);
        }
    }
    __syncthreads();
    if (tid < 8) {
        int s = 0;
        for (int i = 0; i < 32; ++i) { off[tid][i] = s; s += cnt[tid][i]; cnt[tid][i] = 0; }
    }
    __syncthreads();
    if (tid < T) {
#pragma unroll
        for (int p = 0; p < 4; ++p) {
            int c = (cc >> (8 * p)) & 0xff; if (c > 31) c = 31;
            int sidx = p * 2 + half;
            int rank = off[sidx][c] + atomicAdd(&cnt[sidx][c], 1);
            perm[((size_t)b * 8 + sidx) * 128 + rank] = (unsigned char)lt;
        }
    }
}

// ---------------- hidden layer: 38.5 KB LDS -> 4 blocks/CU (32 waves/CU) ----
// r7-proven gather structure + r14-proven u32[b][s][t] hsbits layout (each
// block writes 250 consecutive u32 -> full lines, one XCD, no partial-line
// RMW; WRITE_SIZE 64 MB -> 8.2 MB measured). Summation order unchanged.
__global__ void __launch_bounds__(512, 8)
hidden_slice3(const unsigned short* __restrict__ lists,
              const unsigned* __restrict__ nrow,
              const unsigned char* __restrict__ perm,
              const float* __restrict__ Wt,
              const float* __restrict__ hs0,
              const float* __restrict__ hv0,
              unsigned* __restrict__ hsb32) {
    __shared__ float wlds[176 * 32];   // 22,528 B (row 175 = zeros)
    __shared__ float cur[125 * 32];    // 16,000 B

    int s    = blockIdx.x;        // 0..31 h-slice
    int b    = blockIdx.y;        // 0..255
    int tid  = threadIdx.x;
    int wv   = tid >> 6;
    int lane = tid & 63;
    int g    = lane >> 3;
    int li   = lane & 7;
    int lxor = li << 4;
    int l    = lane & 31;

    float keep = 0.0f;
    if (wv == 0) {
        int h = s * 32 + l;
        keep = hv0[b * H + h] * 0.5f * (1.0f - hs0[b * H + h]);
    }
    unsigned* hp = hsb32 + ((size_t)b * 32 + s) * T;   // this block's 250-u32 run

    for (int th = 0; th < 2; ++th) {
        for (int p = 0; p < 4; ++p) {
            // ---- stage quarter-Wt slice, swizzled: slot = lis ^ (jl&7) ----
            {
                int jr  = tid >> 3;            // 0..63
                int lis = tid & 7;
#pragma unroll
                for (int bj = 0; bj < 192; bj += 64) {
                    int jl = bj + jr;
                    if (jl < 176) {
                        float4 v = make_float4(0.0f, 0.0f, 0.0f, 0.0f);
                        if (jl < 175)
                            v = *(const float4*)(Wt + (size_t)(p * 175 + jl) * H + s * 32 + lis * 4);
                        *(float4*)((char*)wlds + jl * 128 + ((lis ^ (jl & 7)) << 4)) = v;
                    }
                }
            }
            __syncthreads();

            const unsigned char* pm = perm + ((size_t)b * 8 + p * 2 + th) * 128;

            // ---- gather: 125 rows, 64 groups -> 2 sweeps ----
#pragma unroll
            for (int sweep = 0; sweep < 2; ++sweep) {
                int rr = sweep * 64 + wv * 8 + g;
                if (rr < 125) {
                    int lr  = pm[rr];
                    int r   = th * 125 + lr;
                    int row = b * T + r;
                    unsigned cc = nrow[row];
                    int c = (cc >> (8 * p)) & 0xff;
                    int offc = 0;
                    if (p > 0) offc += (cc & 0xff);
                    if (p > 1) offc += ((cc >> 8) & 0xff);
                    if (p > 2) offc += ((cc >> 16) & 0xff);
                    const uint2* qp = (const uint2*)(lists + (size_t)row * LMAX + offc * 4);
                    char* cp = (char*)cur + lr * 128 + ((li ^ (lr & 7)) << 4);

                    float a0, a1, a2, a3;
                    if (p == 0) {
                        a0 = a1 = a2 = a3 = 0.0f;
                    } else {
                        float4 cv = *(const float4*)cp;
                        a0 = cv.x; a1 = cv.y; a2 = cv.z; a3 = cv.w;
                    }

                    if (c > 0) {
                        uint2 w2 = qp[0];
                        int ch = 0;
                        for (;;) {
                            uint2 nw = (ch + 1 < c) ? qp[ch + 1] : w2;
                            int e0 = w2.x & 0xffff, e1 = w2.x >> 16;
                            int e2 = w2.y & 0xffff, e3 = w2.y >> 16;
                            float4 v0 = *(const float4*)((char*)wlds + (e0 ^ lxor));
                            float4 v1 = *(const float4*)((char*)wlds + (e1 ^ lxor));
                            float4 v2 = *(const float4*)((char*)wlds + (e2 ^ lxor));
                            float4 v3 = *(const float4*)((char*)wlds + (e3 ^ lxor));
                            a0 += v0.x; a1 += v0.y; a2 += v0.z; a3 += v0.w;
                            a0 += v1.x; a1 += v1.y; a2 += v1.z; a3 += v1.w;
                            a0 += v2.x; a1 += v2.y; a2 += v2.z; a3 += v2.w;
                            a0 += v3.x; a1 += v3.y; a2 += v3.z; a3 += v3.w;
                            ++ch;
                            if (ch >= c) break;
                            w2 = nw;
                        }
                    }
                    float4 o; o.x = a0; o.y = a1; o.z = a2; o.w = a3;
                    *(float4*)cp = o;
                }
            }
            __syncthreads();
        }

        // ---- scan this t-half: wave 0 (lanes 32-63 mirror), 32 h ----
        if (wv == 0) {
            for (int lt = 0; lt < 125; ++lt) {
                float cv = *(const float*)((char*)cur + lt * 128 +
                                           (((l >> 2) ^ (lt & 7)) << 4) + (l & 3) * 4);
                float hv = keep + cv;
                bool sp = hv > 0.5f;
                keep = sp ? 0.0f : hv * 0.5f;
                u64 ball = __ballot(sp);
                if (lane == 0)
                    hp[th * 125 + lt] = (unsigned)ball;
            }
        }
        __syncthreads();   // protect cur before next half overwrites
    }
}

// ---------------- fallback: round-0 fused hidden kernel (new hsbits layout) ----
__global__ void __launch_bounds__(1024)
hidden_fused(const u64* __restrict__ bits,
             const float* __restrict__ Wt,
             const float* __restrict__ hs0,
             const float* __restrict__ hv0,
             unsigned* __restrict__ hsb32) {
    __shared__ int idx_l[2][256];

    int b = blockIdx.x;
    int h = threadIdx.x;
    int wv   = h >> 6;
    int lane = h & 63;

    float keep = hv0[b * H + h] * 0.5f * (1.0f - hs0[b * H + h]);

    const u64* bb = bits + (size_t)b * T * NW_INP;

    for (int t = 0; t < T; ++t) {
        const u64* wp = bb + (size_t)t * NW_INP;
        u64 w[NW_IN];
#pragma unroll
        for (int k = 0; k < NW_IN; ++k) w[k] = wp[k];

        int base[NW_IN + 1];
        base[0] = 0;
#pragma unroll
        for (int k = 0; k < NW_IN; ++k) base[k + 1] = base[k] + __popcll(w[k]);
        int n = base[NW_IN];

        int buf = t & 1;
        if (wv < NW_IN) {
            u64 m = w[wv];
            if ((m >> lane) & 1ull) {
                int pos = base[wv] + __popcll(m & ((1ull << lane) - 1ull));
                idx_l[buf][pos] = (wv << 6) + lane;
            }
        }
        __syncthreads();

        const int* il = idx_l[buf];
        float cur2 = 0.0f;
        int i = 0;
        for (; i + 8 <= n; i += 8) {
            int j0 = il[i + 0], j1 = il[i + 1], j2 = il[i + 2], j3 = il[i + 3];
            int j4 = il[i + 4], j5 = il[i + 5], j6 = il[i + 6], j7 = il[i + 7];
            float v0 = Wt[(size_t)j0 * H + h];
            float v1 = Wt[(size_t)j1 * H + h];
            float v2 = Wt[(size_t)j2 * H + h];
            float v3 = Wt[(size_t)j3 * H + h];
            float v4 = Wt[(size_t)j4 * H + h];
            float v5 = Wt[(size_t)j5 * H + h];
            float v6 = Wt[(size_t)j6 * H + h];
            float v7 = Wt[(size_t)j7 * H + h];
            cur2 += v0; cur2 += v1; cur2 += v2; cur2 += v3;
            cur2 += v4; cur2 += v5; cur2 += v6; cur2 += v7;
        }
        for (; i < n; ++i) cur2 += Wt[(size_t)il[i] * H + h];

        float hv = keep + cur2;
        bool sp = hv > 0.5f;
        keep = sp ? 0.0f : hv * 0.5f;
        u64 ball = __ballot(sp);
        if (lane == 0) {
            hsb32[((size_t)b * 32 + 2 * wv + 0) * T + t] = (unsigned)ball;
            hsb32[((size_t)b * 32 + 2 * wv + 1) * T + t] = (unsigned)(ball >> 32);
        }
    }
}

// ---------------- output currents v2: LDS-staged WoT, 3 rows/wave ----------------
__global__ void __launch_bounds__(512)
out_currents2(const unsigned* __restrict__ hsb32,
              const float* __restrict__ WoT,
              float* __restrict__ Iout) {
    __shared__ float wot[H * DOUT];   // 81,920 B

    int tid = threadIdx.x;
    {
        const float4* src = (const float4*)WoT;
        float4* dst = (float4*)wot;
#pragma unroll
        for (int k = 0; k < 10; ++k)
            dst[k * 512 + tid] = src[k * 512 + tid];
    }
    __syncthreads();

    int wv   = tid >> 6;
    int lane = tid & 63;
    int sub  = lane / 20;             // 0..3 (3 = idle)
    int o    = lane - sub * 20;
    int row  = blockIdx.x * 24 + wv * 3 + sub;
    if (sub >= 3 || row >= B * T) return;

    int b = row / T;
    int t = row - b * T;
    const unsigned* hb = hsb32 + (size_t)b * 32 * T + t;

    unsigned w[32];
#pragma unroll
    for (int k = 0; k < 32; ++k) w[k] = hb[(size_t)k * T];

    float acc = 0.0f;
#pragma unroll
    for (int k = 0; k < 32; ++k) {
        unsigned m = w[k];
        const float* basep = wot + k * 32 * DOUT + o;
        while (m) {
            int h0 = __builtin_ctz(m);
            m &= m - 1;
            acc += basep[h0 * DOUT];
        }
    }
    Iout[(size_t)row * DOUT + o] = acc;
}

// ---------------- output scan + spike count (LDS-staged) ----------------
__global__ void __launch_bounds__(256)
out_scan(const float* __restrict__ Iout,
         const float* __restrict__ os0,
         const float* __restrict__ ov0,
         float* __restrict__ outp) {
    __shared__ float pan[T * DOUT];   // 20,000 B

    int b   = blockIdx.x;
    int tid = threadIdx.x;

    const float* src = Iout + (size_t)b * T * DOUT;
#pragma unroll
    for (int k = 0; k < 20; ++k) {
        int i = k * 256 + tid;
        if (i < T * DOUT) pan[i] = src[i];
    }
    __syncthreads();

    if (tid < DOUT) {
        int o = tid;
        int idx = b * DOUT + o;
        float ov = ov0[idx];
        float os = os0[idx];
        float keep = ov * 0.5f * (1.0f - os);
        float cnt = 0.0f;
#pragma unroll 5
        for (int t = 0; t < T; ++t) {
            float v = keep + pan[t * DOUT + o];
            float sp = (v > 0.5f) ? 1.0f : 0.0f;
            cnt += sp;
            keep = v * 0.5f * (1.0f - sp);
        }
        outp[idx] = cnt;
    }
}

extern "C" void kernel_launch(void* const* d_in, const int* in_sizes, int n_in,
                              void* d_out, int out_size, void* d_ws, size_t ws_size,
                              hipStream_t stream) {
    const float* spike = (const float*)d_in[0];   // [256][700][250]
    const float* W_hid = (const float*)d_in[1];   // [1024][700]
    const float* W_out = (const float*)d_in[2];   // [20][1024]
    const float* hs0   = (const float*)d_in[3];   // [256][1024]
    const float* hv0   = (const float*)d_in[4];
    const float* os0   = (const float*)d_in[5];   // [256][20]
    const float* ov0   = (const float*)d_in[6];
    float* outp = (float*)d_out;                  // [256][20]

    char* ws = (char*)d_ws;
    float*          Wt     = (float*)(ws);                      // 2,867,200 B
    float*          WoT    = (float*)(ws + 2867200);            //    81,920 B
    u64*            bits   = (u64*)  (ws + 2949120);            // 6,144,000 B
    unsigned*       hsb32  = (unsigned*)(ws + 9093120);         // 8,192,000 B
    float*          Iout   = (float*)(ws + 17285120);           // 5,120,000 B
    unsigned short* lists  = (unsigned short*)(ws + 22405120);  // 20,480,000 B
    unsigned*       nrow   = (unsigned*)(ws + 42885120);        //   256,000 B
    unsigned char*  perm   = (unsigned char*)(ws + 43141120);   //   262,144 B
    const size_t need = 43403264;

    prep_all<<<3904, 256, 0, stream>>>(W_hid, W_out, spike, Wt, WoT, bits);

    if (ws_size >= need) {
        prep_lists2<<<16000, 256, 0, stream>>>(bits, lists, nrow);
        sort_rows<<<B, 256, 0, stream>>>(nrow, perm);
        hidden_slice3<<<dim3(32, 256), 512, 0, stream>>>(lists, nrow, perm, Wt, hs0, hv0, hsb32);
    } else {
        hidden_fused<<<B, 1024, 0, stream>>>(bits, Wt, hs0, hv0, hsb32);
    }

    out_currents2<<<2667, 512, 0, stream>>>(hsb32, WoT, Iout);
    out_scan<<<B, 256, 0, stream>>>(Iout, os0, ov0, outp);
}